// Round 16
// baseline (197.348 us; speedup 1.0000x reference)
//
#include <hip/hip_runtime.h>
#include <hip/hip_bf16.h>

typedef __attribute__((ext_vector_type(8))) short bf16x8;
typedef __attribute__((ext_vector_type(4))) float f32x4;
typedef unsigned short u16;
typedef unsigned int u32;

#define NP 34                                           // 32 + 2 halo
#define XT_BYTES ((size_t)4 * NP * NP * NP * 128 * 2)   // 40,247,296 B

__device__ __forceinline__ u16 f2bf(float f) {
  __hip_bfloat16 h = __float2bfloat16(f);
  return __builtin_bit_cast(u16, h);
}

__device__ __forceinline__ void gload_lds16(const u16* g, u16* l) {
  __builtin_amdgcn_global_load_lds(
      (const __attribute__((address_space(1))) u32*)g,
      (__attribute__((address_space(3))) u32*)l, 16, 0, 0);
}

#define WAITV(N) asm volatile("s_waitcnt vmcnt(" #N ")" ::: "memory")
#define BAR() do { __builtin_amdgcn_s_barrier(); asm volatile("" ::: "memory"); } while (0)

// ---------------- kernel 1: demod + modulated bf16 weights ----------------
__global__ __launch_bounds__(128) void kmodw(const float* __restrict__ w,
                                             const float* __restrict__ y,
                                             u16* __restrict__ wmod) {
  const int oc = blockIdx.x, b = blockIdx.y;
  const int ic = threadIdx.x;               // 128 threads
  const float* wp = w + (oc * 128 + ic) * 27;
  float wv[27];
  float s = 0.f;
#pragma unroll
  for (int t = 0; t < 27; ++t) { wv[t] = wp[t]; s += wv[t] * wv[t]; }
  const float yv = y[b * 128 + ic];
  float v = yv * yv * s;
#pragma unroll
  for (int m = 1; m < 64; m <<= 1) v += __shfl_xor(v, m);
  __shared__ float part[2];
  const int lane = ic & 63, wid = ic >> 6;
  if (lane == 0) part[wid] = v;
  __syncthreads();
  const float demod = rsqrtf(part[0] + part[1] + 1e-8f);
  const float sc = yv * demod;
#pragma unroll
  for (int t = 0; t < 27; ++t)
    wmod[((b * 27 + t) * 128 + oc) * 128 + ic] = f2bf(wv[t] * sc);
}

// ---------------- kernel 2: zero only the halo of xt ----------------------
__global__ __launch_bounds__(128) void khalo(u16* __restrict__ xt) {
  const int zy = blockIdx.x, b = blockIdx.y;
  const int zz = zy / NP, yy = zy % NP;
  u16* row = xt + ((size_t)((b * NP + zz) * NP + yy) * NP) * 128;
  u32* wp = (u32*)row;                      // 34*128 u16 = 2176 u32
  if (zz == 0 || zz == NP - 1 || yy == 0 || yy == NP - 1) {
#pragma unroll
    for (int i = 0; i < 17; ++i) wp[i * 128 + threadIdx.x] = 0;
  } else {
    if (threadIdx.x < 64) wp[threadIdx.x] = 0;
    else ((u32*)(row + 33 * 128))[threadIdx.x - 64] = 0;
  }
}

// ---------------- kernel 3: f32 -> bf16 transpose-cast (interior) ----------
__global__ __launch_bounds__(256) void kcastx(const float* __restrict__ x,
                                              u16* __restrict__ xt) {
  const int yq = blockIdx.x, z = blockIdx.y, b = blockIdx.z;
  const int tid = threadIdx.x;
  __shared__ u16 t[32 * 132];               // [x][ic], stride 132 kills conflicts
  const float* xp = x + (size_t)b * 128 * 32768 + (z * 32 + yq) * 32;
#pragma unroll
  for (int p = 0; p < 16; ++p) {
    const int ic = p * 8 + (tid >> 5), xx = tid & 31;
    t[xx * 132 + ic] = f2bf(xp[(size_t)ic * 32768 + xx]);
  }
  __syncthreads();
  u16* xtb = xt + (((size_t)(b * NP + z + 1) * NP + (yq + 1)) * NP + 1) * 128;
#pragma unroll
  for (int p = 0; p < 4; ++p) {
    const int xx = p * 8 + (tid >> 5), icq = tid & 31;
    *(ushort4*)(xtb + (size_t)xx * 128 + icq * 4) = *(const ushort4*)&t[xx * 132 + icq * 4];
  }
}

// ---------------- kernel 4: quarter-K, tri-A, unrolled-tap conv -----------
// Block: 128 oc x 128 n (4y x 32x at fixed z), 2 waves, wave tile 128x64.
// 108 K-steps = 12 groups (q outer, dz inner) x 9 unrolled taps (dy,dx).
// A: [oc][4 slot] 8 KB/step, tri-buffered, staged 2 ahead, counted WAITV(4).
// B: 6-strip x 34 x 32ic plane (13 KB) per group, 9x tap reuse via offsets.
// Slot swizzle sl = sgq ^ ((r ^ (r>>2)) & 3) both-sides (2-way = free).
// 38.9 KB LDS -> 4 independent blocks/CU (8 waves), 2-wave barriers.
__global__ __launch_bounds__(128, 2) void kconv(const u16* __restrict__ xt,
                                                const u16* __restrict__ wmod,
                                                float* __restrict__ out) {
  __shared__ __align__(16) u16 Asm[3][4096];   // 3 x 8 KiB: row=oc, 4x16B slots
  __shared__ __align__(16) u16 Bsm[7168];      // 14336 B: 204 rows + pad
  const int tid = threadIdx.x;                 // 0..127
  const int lane = tid & 63, wn = tid >> 6;    // 2 waves along n
  const int l15 = lane & 15, sgq = lane >> 4;
  const int bid = blockIdx.x;                  // 1024 blocks
  const int wgid = ((bid & 7) << 7) + (bid >> 3);   // XCD swizzle (1024%8==0)
  const int b = wgid >> 8, yt = (wgid >> 5) & 7, z = wgid & 31;
  const int y0 = yt << 2;

  const u16* wb = wmod + (size_t)b * 27 * 16384;
  const u16* xb = xt + (size_t)b * (NP * NP * NP) * 128;

  f32x4 acc[8][4];
#pragma unroll
  for (int i = 0; i < 8; ++i)
#pragma unroll
    for (int j = 0; j < 4; ++j) acc[i][j] = (f32x4){0.f, 0.f, 0.f, 0.f};

  // ---- A staging constants (4 loads/thread; row0 = tid>>2) ----
  const int arow0 = tid >> 2;
  const int av0 = (arow0 ^ (arow0 >> 2)) & 3;          // invariant under +32
  const int aoff0 = arow0 * 128 + (((tid & 3) ^ av0) << 3);
  const int adst0 = tid << 3;
  // ---- A fragment read base: sl constant per lane ----
  const int slA = sgq ^ ((l15 ^ (l15 >> 2)) & 3);
  const int afb = l15 * 32 + (slA << 3);
  // ---- B fragment rows ----
  int rb[4];
#pragma unroll
  for (int nf = 0; nf < 4; ++nf) {
    const int n = (wn << 6) + (nf << 4) + l15;
    rb[nf] = ((n >> 5) + 1) * 34 + (n & 31) + 1;       // (yy+1)*34 + xx+1
  }

  auto stageA = [&](int tap, int q32, int par) {       // 4 gload_lds
    const u16* src = wb + tap * 16384 + q32 + aoff0;
    u16* dst = &Asm[par][adst0];
#pragma unroll
    for (int k = 0; k < 4; ++k)
      gload_lds16(src + (k << 12), dst + (k << 10));
  };
  auto stageB = [&](int q, int dzi) {                  // 7 gload_lds
    const int pz = z + dzi;
#pragma unroll
    for (int r7 = 0; r7 < 7; ++r7) {
      int s = (r7 << 7) + tid;
      const int dst = s << 3;                          // UNCLAMPED dest
      s = s < 815 ? s : 815;
      const int r = s >> 2, jj = s & 3;
      const int sy = r / 34, x = r - sy * 34;
      const int vr = (r ^ (r >> 2)) & 3;
      gload_lds16(xb + ((size_t)(pz * NP + (y0 + sy)) * NP + x) * 128 +
                      (q << 5) + ((jj ^ vr) << 3),
                  &Bsm[dst]);
    }
  };

  bf16x8 af[8], bv[4];

#define LDAF(PAR)                                                          \
  { const u16* Ah = &Asm[PAR][afb];                                        \
    _Pragma("unroll") for (int m = 0; m < 8; ++m)                          \
      af[m] = *(const bf16x8*)&Ah[m << 9]; }
#define LDBV(D)                                                            \
  { _Pragma("unroll") for (int nf = 0; nf < 4; ++nf) {                     \
      const int row = rb[nf] + (D);                                        \
      const int v = (row ^ (row >> 2)) & 3;                                \
      bv[nf] = *(const bf16x8*)&Bsm[(row << 5) + ((sgq ^ v) << 3)]; } }
#define MFMA32()                                                           \
  { __builtin_amdgcn_s_setprio(1);                                         \
    _Pragma("unroll") for (int mm = 0; mm < 8; ++mm)                       \
      _Pragma("unroll") for (int nf = 0; nf < 4; ++nf)                     \
        acc[mm][nf] = __builtin_amdgcn_mfma_f32_16x16x32_bf16(             \
            af[mm], bv[nf], acc[mm][nf], 0, 0, 0);                         \
    __builtin_amdgcn_s_setprio(0); }

  // prologue: B(g=0:q0,dz0) + A(step0: tap0,q0) + A(step1: tap1,q0)
  stageB(0, 0);
  stageA(0, 0, 0);
  stageA(1, 0, 1);
  WAITV(0); BAR();

  int q32 = 0, dzi = 0;                        // current group params
  for (int g = 0; g < 12; ++g) {
    const int gn = g + 1;
    const int qn = gn < 12 ? gn / 3 : 0;
    const int dzn = gn < 12 ? gn - qn * 3 : 0;
    const int qn32 = qn << 5;
#pragma unroll
    for (int j = 0; j < 9; ++j) {
      // stage A(ks+2): par = (j+2)%3 (9g ≡ 0 mod 3)
      if (j <= 6) {
        stageA(dzi * 9 + j + 2, q32, (j + 2) % 3);
      } else if (g < 11) {                     // crosses into group g+1
        stageA(dzn * 9 + (j - 7), qn32, (j + 2) % 3);
      }
      // fragments + MFMA (dy/dx compile-time)
      LDAF(j % 3);
      LDBV((j / 3 - 1) * 34 + (j % 3 - 1));
      MFMA32();
      // boundary
      if (j < 8) {
        if (j == 7 && g == 11) { WAITV(0); BAR(); }    // tail: no stage issued
        else { WAITV(4); BAR(); }              // drain A(ks+1), keep A(ks+2)
      } else if (g < 11) {
        BAR();                                 // B(g) reads complete
        stageB(qn, dzn);
        WAITV(0); BAR();                       // B(g+1) + A prefetch published
      }
    }
    q32 = qn32; dzi = dzn;
  }

  // epilogue: C/D col=l15 (n), row=sgq*4+r (oc within 16)
#pragma unroll
  for (int m = 0; m < 8; ++m) {
    const int ocb = (m << 4) + (sgq << 2);
#pragma unroll
    for (int nf = 0; nf < 4; ++nf) {
      const int n = (wn << 6) + (nf << 4) + l15;
      const int yy = n >> 5, xx = n & 31;
      float* op = out + ((size_t)(b * 128 + ocb) << 15) + (z << 10) +
                  ((y0 + yy) << 5) + xx;
#pragma unroll
      for (int r = 0; r < 4; ++r) op[(size_t)r << 15] = acc[m][nf][r];
    }
  }
#undef LDAF
#undef LDBV
#undef MFMA32
}

extern "C" void kernel_launch(void* const* d_in, const int* in_sizes, int n_in,
                              void* d_out, int out_size, void* d_ws, size_t ws_size,
                              hipStream_t stream) {
  const float* x = (const float*)d_in[0];
  const float* y = (const float*)d_in[1];
  const float* w = (const float*)d_in[2];
  float* out = (float*)d_out;
  u16* xt = (u16*)d_ws;
  u16* wmod = (u16*)((char*)d_ws + XT_BYTES);

  hipLaunchKernelGGL(khalo, dim3(NP * NP, 4), dim3(128), 0, stream, xt);
  hipLaunchKernelGGL(kmodw, dim3(128, 4), dim3(128), 0, stream, w, y, wmod);
  hipLaunchKernelGGL(kcastx, dim3(32, 32, 4), dim3(256), 0, stream, x, xt);
  hipLaunchKernelGGL(kconv, dim3(1024), dim3(128), 0, stream, xt, wmod, out);
}

// Round 17
// 116.428 us; speedup vs baseline: 1.6950x; 1.6950x over previous
//
#include <hip/hip_runtime.h>
#include <hip/hip_bf16.h>

typedef __attribute__((ext_vector_type(8))) short bf16x8;
typedef __attribute__((ext_vector_type(4))) float f32x4;
typedef unsigned short u16;
typedef unsigned int u32;

#define NP 34                                           // 32 + 2 halo
#define XT_BYTES ((size_t)4 * NP * NP * NP * 128 * 2)   // 40,247,296 B

__device__ __forceinline__ u16 f2bf(float f) {
  __hip_bfloat16 h = __float2bfloat16(f);
  return __builtin_bit_cast(u16, h);
}

__device__ __forceinline__ void gload_lds16(const u16* g, u16* l) {
  __builtin_amdgcn_global_load_lds(
      (const __attribute__((address_space(1))) u32*)g,
      (__attribute__((address_space(3))) u32*)l, 16, 0, 0);
}

#define WAITV(N) asm volatile("s_waitcnt vmcnt(" #N ")" ::: "memory")
#define BAR() do { __builtin_amdgcn_s_barrier(); asm volatile("" ::: "memory"); } while (0)

// ---------------- kernel 1: fused halo-zero + demod/modulated weights -----
// blocks [0, NP*NP): zero xt halo row (zz,yy). blocks [NP*NP, NP*NP+128):
// oc = bid - NP*NP, compute wmod[b][tap][oc][ic].
__global__ __launch_bounds__(128) void kprep(const float* __restrict__ w,
                                             const float* __restrict__ y,
                                             u16* __restrict__ wmod,
                                             u16* __restrict__ xt) {
  const int bidx = blockIdx.x, b = blockIdx.y;
  if (bidx < NP * NP) {                     // ---- khalo part ----
    const int zz = bidx / NP, yy = bidx % NP;
    u16* row = xt + ((size_t)((b * NP + zz) * NP + yy) * NP) * 128;
    u32* wp = (u32*)row;                    // 34*128 u16 = 2176 u32
    if (zz == 0 || zz == NP - 1 || yy == 0 || yy == NP - 1) {
#pragma unroll
      for (int i = 0; i < 17; ++i) wp[i * 128 + threadIdx.x] = 0;
    } else {
      if (threadIdx.x < 64) wp[threadIdx.x] = 0;
      else ((u32*)(row + 33 * 128))[threadIdx.x - 64] = 0;
    }
    return;
  }
  // ---- kmodw part ----
  const int oc = bidx - NP * NP;
  const int ic = threadIdx.x;               // 128 threads
  const float* wp = w + (oc * 128 + ic) * 27;
  float wv[27];
  float s = 0.f;
#pragma unroll
  for (int t = 0; t < 27; ++t) { wv[t] = wp[t]; s += wv[t] * wv[t]; }
  const float yv = y[b * 128 + ic];
  float v = yv * yv * s;
#pragma unroll
  for (int m = 1; m < 64; m <<= 1) v += __shfl_xor(v, m);
  __shared__ float part[2];
  const int lane = ic & 63, wid = ic >> 6;
  if (lane == 0) part[wid] = v;
  __syncthreads();
  const float demod = rsqrtf(part[0] + part[1] + 1e-8f);
  const float sc = yv * demod;
#pragma unroll
  for (int t = 0; t < 27; ++t)
    wmod[((b * 27 + t) * 128 + oc) * 128 + ic] = f2bf(wv[t] * sc);
}

// ---------------- kernel 2: f32 -> bf16 transpose-cast (interior) ----------
__global__ __launch_bounds__(256) void kcastx(const float* __restrict__ x,
                                              u16* __restrict__ xt) {
  const int yq = blockIdx.x, z = blockIdx.y, b = blockIdx.z;
  const int tid = threadIdx.x;
  __shared__ u16 t[32 * 132];               // [x][ic], stride 132 kills conflicts
  const float* xp = x + (size_t)b * 128 * 32768 + (z * 32 + yq) * 32;
#pragma unroll
  for (int p = 0; p < 16; ++p) {
    const int ic = p * 8 + (tid >> 5), xx = tid & 31;
    t[xx * 132 + ic] = f2bf(xp[(size_t)ic * 32768 + xx]);
  }
  __syncthreads();
  u16* xtb = xt + (((size_t)(b * NP + z + 1) * NP + (yq + 1)) * NP + 1) * 128;
#pragma unroll
  for (int p = 0; p < 4; ++p) {
    const int xx = p * 8 + (tid >> 5), icq = tid & 31;
    *(ushort4*)(xtb + (size_t)xx * 128 + icq * 4) = *(const ushort4*)&t[xx * 132 + icq * 4];
  }
}

// ---------------- kernel 3: R14 schedule + cross-step bv0 prefetch --------
// Block: 128 oc x 256 n (8y x 32x at fixed z), 4 waves, wave tile 128x64.
// 54 K-steps = 6 groups (dz,h) x 9 taps (dy,dx). B plane (10 strips x 34 x
// x 64ic = 44 KiB) staged once per group, 9x reuse. A double-buffered
// (2x16 KiB), staged 1 step ahead, drain-style WAITV(0) at step end.
// NEW: next step's kk0 B-fragments (bvP) are ds_read BEFORE the step-end
// barrier (Bsm immutable within a group) -> post-barrier critical path is
// only the 4 af reads. 76 KiB LDS -> 2 independent blocks/CU.
__global__ __launch_bounds__(256, 2) void kconv(const u16* __restrict__ xt,
                                                const u16* __restrict__ wmod,
                                                float* __restrict__ out) {
  __shared__ __align__(16) u16 Asm[2][8192];   // 2 x 16 KiB [oc 128][64 ic]
  __shared__ __align__(16) u16 Bsm[22528];     // 44 KiB (2816 x 16B slots)
  const int tid = threadIdx.x;
  const int lane = tid & 63, wn = tid >> 6;    // 4 waves along n
  const int l15 = lane & 15, sgq = lane >> 4;
  const int bid = blockIdx.x;                  // 512 blocks
  const int wgid = ((bid & 7) << 6) + (bid >> 3);   // XCD-bijective swizzle
  const int b = wgid >> 7, yt = (wgid >> 5) & 3, z = wgid & 31;
  const int y0 = yt << 3;

  const u16* wb = wmod + (size_t)b * 27 * 16384;
  const u16* xb = xt + (size_t)b * (NP * NP * NP) * 128;

  f32x4 acc[8][4];
#pragma unroll
  for (int i = 0; i < 8; ++i)
#pragma unroll
    for (int j = 0; j < 4; ++j) acc[i][j] = (f32x4){0.f, 0.f, 0.f, 0.f};

  // A staging: 1024 slots, 4 loads/thread
  const int aoc0 = tid >> 3, aj = tid & 7;
  const u16* asrc = wb + (aoc0 << 7) + ((aj ^ (aoc0 & 7)) << 3);
  const int adst = tid << 3;
  // B fragment per-lane bases: strip = yy+1 (+dy), row-in-strip = x pos
  int sybase[4], xp0[4];
#pragma unroll
  for (int nf = 0; nf < 4; ++nf) {
    sybase[nf] = (((wn << 1) + (nf >> 1)) + 1) * 2176;   // (yy+1)*34*64
    xp0[nf] = ((nf & 1) << 4) + l15 + 1;
  }
  const int kswz0 = sgq ^ (l15 & 7);

  auto stageA = [&](int ks1) {                 // stage A(ks1) -> Asm[ks1&1]
    const int g1 = ks1 / 9, j1 = ks1 - g1 * 9;
    const int tap = (g1 >> 1) * 9 + j1, hh = g1 & 1;
    const u16* base = asrc + tap * 16384 + (hh << 6);
    u16* dst = &Asm[ks1 & 1][adst];
#pragma unroll
    for (int k = 0; k < 4; ++k)
      gload_lds16(base + (k << 12), dst + (k << 11));
  };
  auto stageB = [&](int g) {                   // 11 loads/thread, linear dest
    const int dz = (g >> 1) - 1, hh = g & 1;
    const int zro = (z + 1 + dz) * NP + y0;    // strip sy -> row zro+sy
#pragma unroll
    for (int r = 0; r < 11; ++r) {
      int s = r * 256 + tid;
      const int dst = s << 3;                  // UNCLAMPED (pad absorbs tail)
      s = s < 2719 ? s : 2719;
      const int sy = s / 272;
      const int rem = s - sy * 272;
      const int xpos = rem >> 3, j = rem & 7;
      gload_lds16(xb + (size_t)((zro + sy) * NP + xpos) * 128 + (hh << 6) +
                      ((j ^ (xpos & 7)) << 3),
                  &Bsm[dst]);
    }
  };
  auto ldAf = [&](bf16x8* af, int par, int mh, int kswz) {
    const u16* Ah = &Asm[par][0];
#pragma unroll
    for (int mm = 0; mm < 4; ++mm) {
      const int oc = (mh << 6) + (mm << 4) + l15;
      af[mm] = *(const bf16x8*)&Ah[(oc << 6) + (kswz << 3)];
    }
  };
  auto ldBv = [&](bf16x8* bv, int kk, int dy, int dx) {
#pragma unroll
    for (int nf = 0; nf < 4; ++nf) {
      const int xp = xp0[nf] + dx;
      const int off = sybase[nf] + dy * 2176 + (xp << 6) +
                      ((((kk << 2) + sgq) ^ (xp & 7)) << 3);
      bv[nf] = *(const bf16x8*)&Bsm[off];
    }
  };

  bf16x8 af0[4], af1[4], bvP[4], bv1[4];

#define MFMA16(MH, AF, BV)                                                 \
  { __builtin_amdgcn_s_setprio(1);                                         \
    _Pragma("unroll") for (int mm = 0; mm < 4; ++mm)                       \
      _Pragma("unroll") for (int nf = 0; nf < 4; ++nf)                     \
        acc[(MH) * 4 + mm][nf] = __builtin_amdgcn_mfma_f32_16x16x32_bf16(  \
            (AF)[mm], (BV)[nf], acc[(MH) * 4 + mm][nf], 0, 0, 0);          \
    __builtin_amdgcn_s_setprio(0); }

  // prologue: B(group0) + A(0), full drain once; then prefetch step0 kk0 B
  stageB(0);
  stageA(0);
  WAITV(0); BAR();
  ldBv(bvP, 0, -1, -1);                 // step 0: (dy,dx) = (-1,-1)

  for (int g = 0; g < 6; ++g) {
    for (int j = 0; j < 9; ++j) {
      const int ks = g * 9 + j;
      const int par = ks & 1;
      const int dy = j / 3 - 1, dx = (j % 3) - 1;
      if (ks < 53) stageA(ks + 1);      // into Asm[(ks+1)&1], in flight
      // ---- barrier-free K-step interior (bv0 = prefetched bvP) ----
      ldAf(af0, par, 0, kswz0);
      MFMA16(0, af0, bvP);
      ldAf(af1, par, 1, kswz0);
      MFMA16(1, af1, bvP);
      ldAf(af0, par, 0, kswz0 ^ 4);
      ldBv(bv1, 1, dy, dx);
      MFMA16(0, af0, bv1);
      ldAf(af1, par, 1, kswz0 ^ 4);
      MFMA16(1, af1, bv1);
      // ---- K-step boundary ----
      if (j < 8) {
        // prefetch next step's kk0 B before the barrier (Bsm immutable)
        ldBv(bvP, 0, (j + 1) / 3 - 1, ((j + 1) % 3) - 1);
        WAITV(0); BAR();                // drains A(ks+1) (issued ~1 step ago)
      } else if (g < 5) {
        BAR();                          // all reads of Bsm(group g) done
        stageB(g + 1);
        WAITV(0); BAR();                // B(g+1) + A prefetch visible
        ldBv(bvP, 0, -1, -1);           // first step of next group
      }
    }
  }

  // epilogue: C/D col=l15 (n), row=sgq*4+r (oc within 16)
#pragma unroll
  for (int m = 0; m < 8; ++m) {
    const int ocb = (m << 4) + (sgq << 2);
#pragma unroll
    for (int nf = 0; nf < 4; ++nf) {
      const int n = (wn << 6) + (nf << 4) + l15;
      const int yy = n >> 5, xx = n & 31;
      float* op = out + ((size_t)(b * 128 + ocb) << 15) + (z << 10) +
                  ((y0 + yy) << 5) + xx;
#pragma unroll
      for (int r = 0; r < 4; ++r) op[(size_t)r << 15] = acc[m][nf][r];
    }
  }
#undef MFMA16
}

extern "C" void kernel_launch(void* const* d_in, const int* in_sizes, int n_in,
                              void* d_out, int out_size, void* d_ws, size_t ws_size,
                              hipStream_t stream) {
  const float* x = (const float*)d_in[0];
  const float* y = (const float*)d_in[1];
  const float* w = (const float*)d_in[2];
  float* out = (float*)d_out;
  u16* xt = (u16*)d_ws;
  u16* wmod = (u16*)((char*)d_ws + XT_BYTES);

  hipLaunchKernelGGL(kprep, dim3(NP * NP + 128, 4), dim3(128), 0, stream,
                     w, y, wmod, xt);
  hipLaunchKernelGGL(kcastx, dim3(32, 32, 4), dim3(256), 0, stream, x, xt);
  hipLaunchKernelGGL(kconv, dim3(512), dim3(256), 0, stream, xt, wmod, out);
}